// Round 4
// baseline (342.995 us; speedup 1.0000x reference)
//
#include <hip/hip_runtime.h>
#include <stdint.h>

// ---------- types ----------
typedef __attribute__((ext_vector_type(4))) float  f32x4;
typedef __attribute__((ext_vector_type(8))) short  short8;   // 8 bf16
typedef __attribute__((ext_vector_type(4))) short  short4v;  // 4 bf16
typedef __attribute__((ext_vector_type(4))) int    int4v;

#define MFMA16(a,b,c) __builtin_amdgcn_mfma_f32_16x16x32_bf16((a),(b),(c),0,0,0)

#if defined(__has_builtin)
#if __has_builtin(__builtin_amdgcn_mfma_f32_16x16x16bf16_1k)
#define PV_MFMA(a,b,c) __builtin_amdgcn_mfma_f32_16x16x16bf16_1k((a),(b),(c),0,0,0)
#endif
#endif
#ifndef PV_MFMA
static __device__ __forceinline__ f32x4 pv_mfma_asm(short4v a, short4v b, f32x4 c) {
    asm("v_mfma_f32_16x16x16_bf16 %0, %1, %2, %0" : "+v"(c) : "v"(a), "v"(b));
    return c;
}
#define PV_MFMA(a,b,c) pv_mfma_asm((a),(b),(c))
#endif

static __device__ __forceinline__ unsigned short f2bf(float f) {
    unsigned int u = __float_as_uint(f);
    u += 0x7FFFu + ((u >> 16) & 1u);   // RNE
    return (unsigned short)(u >> 16);
}
static __device__ __forceinline__ float bflo(unsigned int v) { return __uint_as_float(v << 16); }
static __device__ __forceinline__ float bfhi(unsigned int v) { return __uint_as_float(v & 0xFFFF0000u); }
static __device__ __forceinline__ unsigned int packbf(float a, float b) {
    return (unsigned int)f2bf(a) | ((unsigned int)f2bf(b) << 16);
}

// B=2, S=2048, C=512, E=512, H=8, HD=64
// reshape(B,H,S,HD) w/o transpose => per (b,h): contiguous [2048][64] slab.

// =====================================================================
// Kernel 1: fused QKV projection (unchanged from round 3).
// =====================================================================
__global__ __launch_bounds__(256) void qkv_gemm(
    const float* __restrict__ x,
    const float* __restrict__ Wq, const float* __restrict__ bq,
    const float* __restrict__ Wk, const float* __restrict__ bk,
    const float* __restrict__ Wv, const float* __restrict__ bv,
    unsigned short* __restrict__ Qb, unsigned short* __restrict__ Kb,
    unsigned short* __restrict__ Vb)
{
    __shared__ unsigned short As[128 * 40];
    __shared__ unsigned short Bs[128 * 40];

    const int tid  = threadIdx.x;
    const int lane = tid & 63;
    const int wid  = tid >> 6;
    const int g = lane >> 4, c = lane & 15;
    const int wr = wid >> 1, wc = wid & 1;
    const int bm    = blockIdx.x;
    const int widx  = blockIdx.y >> 2;
    const int ntile = blockIdx.y & 3;

    const float* W    = (widx == 0) ? Wq : (widx == 1) ? Wk : Wv;
    const float* bias = (widx == 0) ? bq : (widx == 1) ? bk : bv;
    unsigned short* Y = (widx == 0) ? Qb : (widx == 1) ? Kb : Vb;
    const float* Abase = x + (size_t)bm * 128 * 512;
    const float* Bbase = W + (size_t)ntile * 128 * 512;

    f32x4 acc[4][4];
    #pragma unroll
    for (int m = 0; m < 4; m++)
        #pragma unroll
        for (int n = 0; n < 4; n++) acc[m][n] = (f32x4){0.f, 0.f, 0.f, 0.f};

    for (int kk = 0; kk < 512; kk += 32) {
        #pragma unroll
        for (int i = 0; i < 4; i++) {
            int f  = i * 256 + tid;
            int rr = f >> 3;
            int cc = (f & 7) * 4;
            f32x4 va = *(const f32x4*)(Abase + rr * 512 + kk + cc);
            f32x4 vb = *(const f32x4*)(Bbase + rr * 512 + kk + cc);
            short4v sa, sb;
            #pragma unroll
            for (int q = 0; q < 4; q++) { sa[q] = (short)f2bf(va[q]); sb[q] = (short)f2bf(vb[q]); }
            *(short4v*)(&As[rr * 40 + cc]) = sa;
            *(short4v*)(&Bs[rr * 40 + cc]) = sb;
        }
        __syncthreads();

        short8 af[4], bfr[4];
        #pragma unroll
        for (int m = 0; m < 4; m++) af[m]  = *(const short8*)(&As[(wr * 64 + m * 16 + c) * 40 + g * 8]);
        #pragma unroll
        for (int n = 0; n < 4; n++) bfr[n] = *(const short8*)(&Bs[(wc * 64 + n * 16 + c) * 40 + g * 8]);
        #pragma unroll
        for (int m = 0; m < 4; m++)
            #pragma unroll
            for (int n = 0; n < 4; n++)
                acc[m][n] = MFMA16(af[m], bfr[n], acc[m][n]);
        __syncthreads();
    }

    #pragma unroll
    for (int n = 0; n < 4; n++) {
        int colW = ntile * 128 + wc * 64 + n * 16 + c;
        float bb = bias[colW];
        #pragma unroll
        for (int m = 0; m < 4; m++) {
            #pragma unroll
            for (int r = 0; r < 4; r++) {
                int row = bm * 128 + wr * 64 + m * 16 + g * 4 + r;
                Y[(size_t)row * 512 + colW] = f2bf(acc[m][n][r] + bb);
            }
        }
    }
}

// =====================================================================
// Kernel 1.5: V transpose (unchanged).
// =====================================================================
__global__ __launch_bounds__(256) void v_transpose(
    const unsigned short* __restrict__ Vb, unsigned short* __restrict__ Vt)
{
    __shared__ unsigned short T[8][520];

    const int tid = threadIdx.x;
    const int t   = blockIdx.x;
    const int bh  = blockIdx.y;
    const int b = bh >> 3, h = bh & 7;

    #pragma unroll
    for (int i = 0; i < 2; i++) {
        int idx = i * 256 + tid;
        int j   = idx >> 6;
        int cc  = (idx & 63) * 8;
        short8 v = *(const short8*)(Vb + (size_t)(b * 2048 + h * 256 + t * 8 + j) * 512 + cc);
        *(short8*)(&T[j][cc]) = v;
    }
    __syncthreads();

    const int d   = tid >> 2;
    const int sjb = (tid & 3) * 16;
    unsigned short tmp[16];
    #pragma unroll
    for (int i = 0; i < 16; i++) {
        int sj = sjb + i;
        tmp[i] = T[sj >> 3][(sj & 7) * 64 + d];
    }
    unsigned short* dst = Vt + ((size_t)(bh * 64 + d) * 2048) + t * 64 + sjb;
    *(short8*)(dst)     = *(short8*)(&tmp[0]);
    *(short8*)(dst + 8) = *(short8*)(&tmp[8]);
}

// =====================================================================
// Kernel 2: fused attention — TRANSPOSED QK^T (key-major registers).
// Lane (g,c) holds q=qrow+c, keys g*4+r within each 16-key tile.
// - logits in exp2 domain, packed bf16 in regs (32 tiles x 2 u32)
// - softmax max/denom: per-lane scalar + shfl(16,32) + tiny LDS cross-wave
// - blend+store: pure register f32x4 (no LDS)
// - PV: regs are directly B-frag of v_mfma 16x16x16; V^T A-frags 8B loads
// =====================================================================
__global__ __launch_bounds__(256) void attn_kernel(
    const unsigned short* __restrict__ Qb, const unsigned short* __restrict__ Kb,
    const unsigned short* __restrict__ Vt,
    const float* __restrict__ dist, const int* __restrict__ mask,
    float* __restrict__ attn_out, unsigned short* __restrict__ ctx_bf)
{
    __shared__ float red[4][2][16];     // [wave][max|sum][q]
    __shared__ float Cred[4][16][68];   // [wave][q][d] PV partials

    const int tid = threadIdx.x;
    const int lane = tid & 63, wid = tid >> 6;
    const int g = lane >> 4, c = lane & 15;
    const int g4 = g * 4;

    const int wg  = blockIdx.x + gridDim.x * blockIdx.y;   // 0..2047
    const int qg  = (wg >> 3) & 127;
    const int bh  = (wg & 7) * 2 + ((wg >> 10) & 1);
    const int b = bh >> 3, h = bh & 7;

    const unsigned short* Qh  = Qb + (size_t)b * 1048576 + (size_t)h * 131072;
    const unsigned short* Kh  = Kb + (size_t)b * 1048576 + (size_t)h * 131072;
    const unsigned short* Vth = Vt + (size_t)bh * 131072;       // [64 d][2048 s]
    const float* distb = dist + (size_t)bh * 4194304;
    float*       outb  = attn_out + (size_t)bh * 4194304;
    const int*   maskb = mask + b * 2048;

    const int qrow    = qg * 16;
    const int keybase = wid * 512;

    // Q B-frag: B[k=d][col=q=c] -> Q[qrow+c][ks*32+g*8..+7]
    short8 qf[2];
    #pragma unroll
    for (int ks = 0; ks < 2; ks++)
        qf[ks] = *(const short8*)(Qh + (size_t)(qrow + c) * 64 + ks * 32 + g * 8);

    const unsigned short* Kptr = Kh + (size_t)(keybase + c) * 64;
    const int*            mptr = maskb + keybase + g4;

    const float SC      = 0.18033688011f;   // 0.125 / ln2  (exp2 domain)
    const float MASKVAL = -1803.3688f;      // -1250 / ln2

    // ---------------- phase 1: logits (S^T) + per-lane max ----------------
    unsigned int pl[32][2];                 // per 16-key tile: (r0,r1),(r2,r3)
    float lmax = -3e38f;

    #pragma unroll
    for (int t = 0; t < 32; t++) {
        short8 kf0 = *(const short8*)(Kptr + t * 1024 + g * 8);        // A[row=key][k=d]
        short8 kf1 = *(const short8*)(Kptr + t * 1024 + 32 + g * 8);
        f32x4 z = (f32x4){0.f, 0.f, 0.f, 0.f};
        z = MFMA16(kf0, qf[0], z);          // C[key][q]: lane holds keys g4+r, q=c
        z = MFMA16(kf1, qf[1], z);
        int4v mv = *(const int4v*)(mptr + t * 16);
        float l[4];
        #pragma unroll
        for (int r = 0; r < 4; r++) {
            l[r] = mv[r] ? MASKVAL : z[r] * SC;
            lmax = fmaxf(lmax, l[r]);
        }
        pl[t][0] = packbf(l[0], l[1]);
        pl[t][1] = packbf(l[2], l[3]);
    }
    lmax = fmaxf(lmax, __shfl_xor(lmax, 16));
    lmax = fmaxf(lmax, __shfl_xor(lmax, 32));
    if (g == 0) red[wid][0][c] = lmax;
    __syncthreads();
    const float m = fmaxf(fmaxf(red[0][0][c], red[1][0][c]),
                          fmaxf(red[2][0][c], red[3][0][c]));

    // ---------------- phase 2: exp2 + denom ----------------
    float dsum = 0.f;
    #pragma unroll
    for (int t = 0; t < 32; t++) {
        unsigned int u0 = pl[t][0], u1 = pl[t][1];
        float e0 = exp2f(bflo(u0) - m);
        float e1 = exp2f(bfhi(u0) - m);
        float e2 = exp2f(bflo(u1) - m);
        float e3 = exp2f(bfhi(u1) - m);
        dsum += (e0 + e1) + (e2 + e3);
        pl[t][0] = packbf(e0, e1);
        pl[t][1] = packbf(e2, e3);
    }
    dsum += __shfl_xor(dsum, 16);
    dsum += __shfl_xor(dsum, 32);
    if (g == 0) red[wid][1][c] = dsum;
    __syncthreads();
    const float invd2 = 0.5f / (red[0][1][c] + red[1][1][c] + red[2][1][c] + red[3][1][c]);

    // ---------------- phase 3: blend + store + PV (all in regs) ----------------
    f32x4 cacc[4];
    #pragma unroll
    for (int nd = 0; nd < 4; nd++) cacc[nd] = (f32x4){0.f, 0.f, 0.f, 0.f};

    const size_t qoff = (size_t)(qrow + c) * 2048 + g4;
    const float* drow = distb + qoff;
    float*       orow = outb + qoff;
    const unsigned short* vrow0 = Vth + (size_t)(c) * 2048;
    const unsigned short* vrow1 = Vth + (size_t)(16 + c) * 2048;
    const unsigned short* vrow2 = Vth + (size_t)(32 + c) * 2048;
    const unsigned short* vrow3 = Vth + (size_t)(48 + c) * 2048;

    #pragma unroll
    for (int kb8 = 0; kb8 < 8; kb8++) {
        const int kb = keybase + kb8 * 64;
        f32x4 dv[4];
        #pragma unroll
        for (int tp = 0; tp < 4; tp++)
            dv[tp] = *(const f32x4*)(drow + kb + tp * 16);
        #pragma unroll
        for (int tp = 0; tp < 4; tp++) {
            const int t = kb8 * 4 + tp;
            const unsigned int u0 = pl[t][0], u1 = pl[t][1];
            f32x4 ap;
            ap[0] = fmaf(bflo(u0), invd2, 0.5f * dv[tp][0]);
            ap[1] = fmaf(bfhi(u0), invd2, 0.5f * dv[tp][1]);
            ap[2] = fmaf(bflo(u1), invd2, 0.5f * dv[tp][2]);
            ap[3] = fmaf(bfhi(u1), invd2, 0.5f * dv[tp][3]);
            *(f32x4*)(orow + kb + tp * 16) = ap;

            short4v apb;
            #pragma unroll
            for (int q = 0; q < 4; q++) apb[q] = (short)f2bf(ap[q]);

            const int ko = kb + tp * 16;   // + g4 already in vrow? no: add g4
            short4v vf0 = *(const short4v*)(vrow0 + ko + g4);
            short4v vf1 = *(const short4v*)(vrow1 + ko + g4);
            short4v vf2 = *(const short4v*)(vrow2 + ko + g4);
            short4v vf3 = *(const short4v*)(vrow3 + ko + g4);
            cacc[0] = PV_MFMA(vf0, apb, cacc[0]);   // ctx^T[d][q]
            cacc[1] = PV_MFMA(vf1, apb, cacc[1]);
            cacc[2] = PV_MFMA(vf2, apb, cacc[2]);
            cacc[3] = PV_MFMA(vf3, apb, cacc[3]);
        }
    }

    // ---------------- phase 4: cross-wave PV reduce + ctx store ----------------
    #pragma unroll
    for (int nd = 0; nd < 4; nd++)
        *(f32x4*)(&Cred[wid][c][nd * 16 + g4]) = cacc[nd];
    __syncthreads();

    {
        const int q  = tid >> 4;          // 0..15
        const int dq = (tid & 15) * 4;    // 0..60
        f32x4 s = *(const f32x4*)(&Cred[0][q][dq]);
        #pragma unroll
        for (int w = 1; w < 4; w++) {
            f32x4 t2 = *(const f32x4*)(&Cred[w][q][dq]);
            #pragma unroll
            for (int j = 0; j < 4; j++) s[j] += t2[j];
        }
        short4v cb;
        #pragma unroll
        for (int j = 0; j < 4; j++) cb[j] = (short)f2bf(s[j]);
        *(short4v*)(ctx_bf + (size_t)(b * 2048 + qrow + q) * 512 + h * 64 + dq) = cb;
    }
}

// =====================================================================
// Kernel 3: out = ctx @ Wo^T + bo (unchanged).
// =====================================================================
__global__ __launch_bounds__(256) void out_gemm(
    const unsigned short* __restrict__ A,
    const float* __restrict__ Wo, const float* __restrict__ bo,
    float* __restrict__ out)
{
    __shared__ unsigned short As[128 * 40];
    __shared__ unsigned short Bs[128 * 40];

    const int tid  = threadIdx.x;
    const int lane = tid & 63;
    const int wid  = tid >> 6;
    const int g = lane >> 4, c = lane & 15;
    const int wr = wid >> 1, wc = wid & 1;
    const int bm    = blockIdx.x;
    const int ntile = blockIdx.y;

    const unsigned short* Abase = A + (size_t)bm * 128 * 512;
    const float* Bbase = Wo + (size_t)ntile * 128 * 512;

    f32x4 acc[4][4];
    #pragma unroll
    for (int m = 0; m < 4; m++)
        #pragma unroll
        for (int n = 0; n < 4; n++) acc[m][n] = (f32x4){0.f, 0.f, 0.f, 0.f};

    for (int kk = 0; kk < 512; kk += 32) {
        #pragma unroll
        for (int i = 0; i < 2; i++) {
            int f8 = i * 256 + tid;
            int rr = f8 >> 2;
            int cc = (f8 & 3) * 8;
            short8 va = *(const short8*)(Abase + (size_t)rr * 512 + kk + cc);
            *(short8*)(&As[rr * 40 + cc]) = va;
        }
        #pragma unroll
        for (int i = 0; i < 4; i++) {
            int f  = i * 256 + tid;
            int rr = f >> 3;
            int cc = (f & 7) * 4;
            f32x4 vb = *(const f32x4*)(Bbase + (size_t)rr * 512 + kk + cc);
            short4v sb;
            #pragma unroll
            for (int q = 0; q < 4; q++) sb[q] = (short)f2bf(vb[q]);
            *(short4v*)(&Bs[rr * 40 + cc]) = sb;
        }
        __syncthreads();

        short8 af[4], bfr[4];
        #pragma unroll
        for (int m = 0; m < 4; m++) af[m]  = *(const short8*)(&As[(wr * 64 + m * 16 + c) * 40 + g * 8]);
        #pragma unroll
        for (int n = 0; n < 4; n++) bfr[n] = *(const short8*)(&Bs[(wc * 64 + n * 16 + c) * 40 + g * 8]);
        #pragma unroll
        for (int m = 0; m < 4; m++)
            #pragma unroll
            for (int n = 0; n < 4; n++)
                acc[m][n] = MFMA16(af[m], bfr[n], acc[m][n]);
        __syncthreads();
    }

    #pragma unroll
    for (int n = 0; n < 4; n++) {
        int col = ntile * 128 + wc * 64 + n * 16 + c;
        float bb = bo[col];
        #pragma unroll
        for (int m = 0; m < 4; m++) {
            #pragma unroll
            for (int r = 0; r < 4; r++) {
                int row = bm * 128 + wr * 64 + m * 16 + g * 4 + r;
                out[(size_t)row * 512 + col] = acc[m][n][r] + bb;
            }
        }
    }
}

// =====================================================================
extern "C" void kernel_launch(void* const* d_in, const int* in_sizes, int n_in,
                              void* d_out, int out_size, void* d_ws, size_t ws_size,
                              hipStream_t stream)
{
    const float* x    = (const float*)d_in[0];
    const float* dist = (const float*)d_in[1];
    const int*   mask = (const int*)d_in[2];
    const float* Wq   = (const float*)d_in[3];
    const float* bq   = (const float*)d_in[4];
    const float* Wk   = (const float*)d_in[5];
    const float* bk   = (const float*)d_in[6];
    const float* Wv   = (const float*)d_in[7];
    const float* bv   = (const float*)d_in[8];
    const float* Wo   = (const float*)d_in[9];
    const float* bo   = (const float*)d_in[10];

    float* out      = (float*)d_out;            // (2,2048,512)
    float* attn_out = out + 2097152;            // (2,8,2048,2048)

    char* ws = (char*)d_ws;
    unsigned short* Qb  = (unsigned short*)(ws);                 // 4 MB
    unsigned short* Kb  = (unsigned short*)(ws + (4u << 20));    // 4 MB
    unsigned short* Vb  = (unsigned short*)(ws + (8u << 20));    // 4 MB (linear V)
    unsigned short* Vt  = (unsigned short*)(ws + (12u << 20));   // 4 MB [16][64][2048]
    unsigned short* ctx = (unsigned short*)(ws + (8u << 20));    // reuses Vb

    qkv_gemm   <<<dim3(32, 12), 256, 0, stream>>>(x, Wq, bq, Wk, bk, Wv, bv, Qb, Kb, Vb);
    v_transpose<<<dim3(32, 16), 256, 0, stream>>>(Vb, Vt);
    attn_kernel<<<dim3(128, 16), 256, 0, stream>>>(Qb, Kb, Vt, dist, mask, attn_out, ctx);
    out_gemm   <<<dim3(32, 4),  256, 0, stream>>>(ctx, Wo, bo, out);
}

// Round 5
// 262.853 us; speedup vs baseline: 1.3049x; 1.3049x over previous
//
#include <hip/hip_runtime.h>
#include <stdint.h>

// ---------- types ----------
typedef __attribute__((ext_vector_type(4))) float  f32x4;
typedef __attribute__((ext_vector_type(8))) short  short8;   // 8 bf16
typedef __attribute__((ext_vector_type(4))) short  short4v;  // 4 bf16

#define MFMA16(a,b,c) __builtin_amdgcn_mfma_f32_16x16x32_bf16((a),(b),(c),0,0,0)

typedef __attribute__((address_space(1))) void gv_t;
typedef __attribute__((address_space(3))) void lv_t;
#define GLL16(g,l) __builtin_amdgcn_global_load_lds((const gv_t*)(g), (lv_t*)(l), 16, 0, 0)

static __device__ __forceinline__ unsigned short f2bf(float f) {
    unsigned int u = __float_as_uint(f);
    u += 0x7FFFu + ((u >> 16) & 1u);   // RNE
    return (unsigned short)(u >> 16);
}
static __device__ __forceinline__ float bflo(unsigned int v) { return __uint_as_float(v << 16); }
static __device__ __forceinline__ float bfhi(unsigned int v) { return __uint_as_float(v & 0xFFFF0000u); }
static __device__ __forceinline__ float bf2f(unsigned short v) { return __uint_as_float(((unsigned int)v) << 16); }
static __device__ __forceinline__ unsigned int packbf(float a, float b) {
    return (unsigned int)f2bf(a) | ((unsigned int)f2bf(b) << 16);
}

// B=2, S=2048, C=512, E=512, H=8, HD=64
// reshape(B,H,S,HD) w/o transpose => per (b,h): contiguous [2048][64] slab.

// =====================================================================
// Kernel 1: fused QKV projection (round-3 proven).
// =====================================================================
__global__ __launch_bounds__(256) void qkv_gemm(
    const float* __restrict__ x,
    const float* __restrict__ Wq, const float* __restrict__ bq,
    const float* __restrict__ Wk, const float* __restrict__ bk,
    const float* __restrict__ Wv, const float* __restrict__ bv,
    unsigned short* __restrict__ Qb, unsigned short* __restrict__ Kb,
    unsigned short* __restrict__ Vb)
{
    __shared__ unsigned short As[128 * 40];
    __shared__ unsigned short Bs[128 * 40];

    const int tid  = threadIdx.x;
    const int lane = tid & 63;
    const int wid  = tid >> 6;
    const int g = lane >> 4, c = lane & 15;
    const int wr = wid >> 1, wc = wid & 1;
    const int bm    = blockIdx.x;
    const int widx  = blockIdx.y >> 2;
    const int ntile = blockIdx.y & 3;

    const float* W    = (widx == 0) ? Wq : (widx == 1) ? Wk : Wv;
    const float* bias = (widx == 0) ? bq : (widx == 1) ? bk : bv;
    unsigned short* Y = (widx == 0) ? Qb : (widx == 1) ? Kb : Vb;
    const float* Abase = x + (size_t)bm * 128 * 512;
    const float* Bbase = W + (size_t)ntile * 128 * 512;

    f32x4 acc[4][4];
    #pragma unroll
    for (int m = 0; m < 4; m++)
        #pragma unroll
        for (int n = 0; n < 4; n++) acc[m][n] = (f32x4){0.f, 0.f, 0.f, 0.f};

    for (int kk = 0; kk < 512; kk += 32) {
        #pragma unroll
        for (int i = 0; i < 4; i++) {
            int f  = i * 256 + tid;
            int rr = f >> 3;
            int cc = (f & 7) * 4;
            f32x4 va = *(const f32x4*)(Abase + rr * 512 + kk + cc);
            f32x4 vb = *(const f32x4*)(Bbase + rr * 512 + kk + cc);
            short4v sa, sb;
            #pragma unroll
            for (int q = 0; q < 4; q++) { sa[q] = (short)f2bf(va[q]); sb[q] = (short)f2bf(vb[q]); }
            *(short4v*)(&As[rr * 40 + cc]) = sa;
            *(short4v*)(&Bs[rr * 40 + cc]) = sb;
        }
        __syncthreads();

        short8 af[4], bfr[4];
        #pragma unroll
        for (int m = 0; m < 4; m++) af[m]  = *(const short8*)(&As[(wr * 64 + m * 16 + c) * 40 + g * 8]);
        #pragma unroll
        for (int n = 0; n < 4; n++) bfr[n] = *(const short8*)(&Bs[(wc * 64 + n * 16 + c) * 40 + g * 8]);
        #pragma unroll
        for (int m = 0; m < 4; m++)
            #pragma unroll
            for (int n = 0; n < 4; n++)
                acc[m][n] = MFMA16(af[m], bfr[n], acc[m][n]);
        __syncthreads();
    }

    #pragma unroll
    for (int n = 0; n < 4; n++) {
        int colW = ntile * 128 + wc * 64 + n * 16 + c;
        float bb = bias[colW];
        #pragma unroll
        for (int m = 0; m < 4; m++) {
            #pragma unroll
            for (int r = 0; r < 4; r++) {
                int row = bm * 128 + wr * 64 + m * 16 + g * 4 + r;
                Y[(size_t)row * 512 + colW] = f2bf(acc[m][n][r] + bb);
            }
        }
    }
}

// =====================================================================
// Kernel 1.5: V transpose (unchanged).
// =====================================================================
__global__ __launch_bounds__(256) void v_transpose(
    const unsigned short* __restrict__ Vb, unsigned short* __restrict__ Vt)
{
    __shared__ unsigned short T[8][520];

    const int tid = threadIdx.x;
    const int t   = blockIdx.x;
    const int bh  = blockIdx.y;
    const int b = bh >> 3, h = bh & 7;

    #pragma unroll
    for (int i = 0; i < 2; i++) {
        int idx = i * 256 + tid;
        int j   = idx >> 6;
        int cc  = (idx & 63) * 8;
        short8 v = *(const short8*)(Vb + (size_t)(b * 2048 + h * 256 + t * 8 + j) * 512 + cc);
        *(short8*)(&T[j][cc]) = v;
    }
    __syncthreads();

    const int d   = tid >> 2;
    const int sjb = (tid & 3) * 16;
    unsigned short tmp[16];
    #pragma unroll
    for (int i = 0; i < 16; i++) {
        int sj = sjb + i;
        tmp[i] = T[sj >> 3][(sj & 7) * 64 + d];
    }
    unsigned short* dst = Vt + ((size_t)(bh * 64 + d) * 2048) + t * 64 + sjb;
    *(short8*)(dst)     = *(short8*)(&tmp[0]);
    *(short8*)(dst + 8) = *(short8*)(&tmp[8]);
}

// =====================================================================
// Kernel 2: fused attention (round-3 structure) + global_load_lds dist
// double-buffer pipeline in phase 3. Per-wave dist staging unioned with
// the phase-4 Cred buffer. exp2-domain softmax.
// =====================================================================
__global__ __launch_bounds__(256) void attn_kernel(
    const unsigned short* __restrict__ Qb, const unsigned short* __restrict__ Kb,
    const unsigned short* __restrict__ Vt,
    const float* __restrict__ dist, const int* __restrict__ mask,
    float* __restrict__ attn_out, unsigned short* __restrict__ ctx_bf)
{
    __shared__ unsigned short AP[4][16][72];                     // 9216 B
    __shared__ float red[4][2][16];                              // 512 B
    __shared__ __attribute__((aligned(16))) float UN[8192];      // 32 KB union:
    // phase 3: dist staging [wave][2 buf][16 rows][64 keys] fp32
    // phase 4: Cred [wave][16][68] fp32 (4352 floats)

    const int tid = threadIdx.x;
    const int lane = tid & 63, wid = tid >> 6;
    const int g = lane >> 4, c = lane & 15;

    const int wg  = blockIdx.x + gridDim.x * blockIdx.y;   // 0..2047
    const int qg  = (wg >> 3) & 127;
    const int bh  = (wg & 7) * 2 + ((wg >> 10) & 1);       // XCD-aware
    const int b = bh >> 3, h = bh & 7;

    const unsigned short* Qh  = Qb + (size_t)b * 1048576 + (size_t)h * 131072;
    const unsigned short* Kh  = Kb + (size_t)b * 1048576 + (size_t)h * 131072;
    const unsigned short* Vth = Vt + (size_t)bh * 131072;       // [64 d][2048 s]
    const float* distb = dist + (size_t)bh * 4194304;
    float*       outb  = attn_out + (size_t)bh * 4194304;
    const int*   maskb = mask + b * 2048;

    const int qrow    = qg * 16;
    const int keybase = wid * 512;

    const float SC      = 0.18033688011f;   // 0.125 / ln2 (exp2 domain)
    const float MASKVAL = -1803.3688f;      // -1250 / ln2

    short8 qf[2];
    #pragma unroll
    for (int ks = 0; ks < 2; ks++)
        qf[ks] = *(const short8*)(Qh + (size_t)(qrow + c) * 64 + ks * 32 + g * 8);

    // ---------------- phase 1: logits + per-wave max ----------------
    unsigned int pl[8][4][2];             // packed bf16 logits [kb8][n][(r0,r1)|(r2,r3)]
    float lmax[4] = {-3e38f, -3e38f, -3e38f, -3e38f};

    #pragma unroll
    for (int kb8 = 0; kb8 < 8; kb8++) {
        const int kb = keybase + kb8 * 64;
        short8 kf[4][2];
        #pragma unroll
        for (int n = 0; n < 4; n++)
            #pragma unroll
            for (int ks = 0; ks < 2; ks++)
                kf[n][ks] = *(const short8*)(Kh + (size_t)(kb + n * 16 + c) * 64 + ks * 32 + g * 8);
        #pragma unroll
        for (int n = 0; n < 4; n++) {
            f32x4 z = (f32x4){0.f, 0.f, 0.f, 0.f};
            z = MFMA16(qf[0], kf[n][0], z);
            z = MFMA16(qf[1], kf[n][1], z);
            const int mv = maskb[kb + n * 16 + c];
            float l[4];
            #pragma unroll
            for (int r = 0; r < 4; r++) {
                l[r] = mv ? MASKVAL : z[r] * SC;
                lmax[r] = fmaxf(lmax[r], l[r]);
            }
            pl[kb8][n][0] = packbf(l[0], l[1]);
            pl[kb8][n][1] = packbf(l[2], l[3]);
        }
    }
    #pragma unroll
    for (int r = 0; r < 4; r++) {
        #pragma unroll
        for (int off = 1; off < 16; off <<= 1)
            lmax[r] = fmaxf(lmax[r], __shfl_xor(lmax[r], off));
    }
    if (c == 0) {
        #pragma unroll
        for (int r = 0; r < 4; r++) red[wid][0][g * 4 + r] = lmax[r];
    }
    __syncthreads();
    float m[4];
    #pragma unroll
    for (int r = 0; r < 4; r++) {
        int row = g * 4 + r;
        m[r] = fmaxf(fmaxf(red[0][0][row], red[1][0][row]),
                     fmaxf(red[2][0][row], red[3][0][row]));
    }

    // ---------------- phase 2: exp2 + denom ----------------
    float dsum[4] = {0.f, 0.f, 0.f, 0.f};
    #pragma unroll
    for (int kb8 = 0; kb8 < 8; kb8++) {
        #pragma unroll
        for (int n = 0; n < 4; n++) {
            #pragma unroll
            for (int pi = 0; pi < 2; pi++) {
                unsigned int v = pl[kb8][n][pi];
                float e0 = exp2f(bflo(v) - m[pi * 2]);
                float e1 = exp2f(bfhi(v) - m[pi * 2 + 1]);
                dsum[pi * 2]     += e0;
                dsum[pi * 2 + 1] += e1;
                pl[kb8][n][pi] = packbf(e0, e1);
            }
        }
    }
    #pragma unroll
    for (int r = 0; r < 4; r++) {
        #pragma unroll
        for (int off = 1; off < 16; off <<= 1)
            dsum[r] += __shfl_xor(dsum[r], off);
    }
    if (c == 0) {
        #pragma unroll
        for (int r = 0; r < 4; r++) red[wid][1][g * 4 + r] = dsum[r];
    }
    __syncthreads();
    float invd[4];
    #pragma unroll
    for (int r = 0; r < 4; r++) {
        int row = g * 4 + r;
        invd[r] = 1.f / (red[0][1][row] + red[1][1][row] + red[2][1][row] + red[3][1][row]);
    }

    // ---------------- phase 3: gll-pipelined dist, blend+store, PV ----------------
    f32x4 cacc[4];
    #pragma unroll
    for (int nd = 0; nd < 4; nd++) cacc[nd] = (f32x4){0.f, 0.f, 0.f, 0.f};

    // per-lane dist source: row qrow + (lane>>4) (+4 per chunk), col (lane&15)*4
    const float* dsrc = distb + (size_t)(qrow + (lane >> 4)) * 2048 + keybase + (lane & 15) * 4;
    float* stg0 = &UN[wid * 2048];          // buffer 0: 1024 floats (16x64)
    float* stg1 = stg0 + 1024;              // buffer 1

    // prologue: stage tile 0
    #pragma unroll
    for (int ch = 0; ch < 4; ch++)
        GLL16(dsrc + ch * 4 * 2048, stg0 + ch * 256);
    __syncthreads();                        // drains vm: tile 0 in LDS

    #pragma unroll
    for (int t = 0; t < 8; t++) {
        const int kb = keybase + t * 64;
        float* cur = (t & 1) ? stg1 : stg0;
        float* nxt = (t & 1) ? stg0 : stg1;

        // (a) issue next tile's gll (in flight across this iteration)
        if (t < 7) {
            const float* ns = dsrc + (t + 1) * 64;
            #pragma unroll
            for (int ch = 0; ch < 4; ch++)
                GLL16(ns + ch * 4 * 2048, nxt + ch * 256);
        }

        // (b) normalized p -> AP in MFMA C-layout
        #pragma unroll
        for (int n = 0; n < 4; n++) {
            #pragma unroll
            for (int pi = 0; pi < 2; pi++) {
                unsigned int v = pl[t][n][pi];
                AP[wid][g * 4 + pi * 2    ][n * 16 + c] = f2bf(bflo(v) * invd[pi * 2]);
                AP[wid][g * 4 + pi * 2 + 1][n * 16 + c] = f2bf(bfhi(v) * invd[pi * 2 + 1]);
            }
        }

        // (c) blend in row-streaming layout; dist from LDS; f32x4 global store
        #pragma unroll
        for (int rg = 0; rg < 4; rg++) {
            const int row = rg * 4 + g;
            f32x4 dvv = *(const f32x4*)(cur + row * 64 + c * 4);
            short4v pv = *(const short4v*)(&AP[wid][row][c * 4]);
            f32x4 apv;
            #pragma unroll
            for (int q = 0; q < 4; q++)
                apv[q] = 0.5f * (bf2f((unsigned short)pv[q]) + dvv[q]);
            *(f32x4*)(outb + (size_t)(qrow + row) * 2048 + kb + c * 4) = apv;
            short4v apb;
            #pragma unroll
            for (int q = 0; q < 4; q++) apb[q] = (short)f2bf(apv[q]);
            *(short4v*)(&AP[wid][row][c * 4]) = apb;
        }

        // (d) PV: A-frags of blended probs from LDS, V from L2
        short8 apf[2];
        #pragma unroll
        for (int ks = 0; ks < 2; ks++)
            apf[ks] = *(const short8*)(&AP[wid][c][ks * 32 + g * 8]);
        #pragma unroll
        for (int nd = 0; nd < 4; nd++) {
            #pragma unroll
            for (int ks = 0; ks < 2; ks++) {
                short8 vf = *(const short8*)(Vth + (size_t)(nd * 16 + c) * 2048 + kb + ks * 32 + g * 8);
                cacc[nd] = MFMA16(apf[ks], vf, cacc[nd]);
            }
        }

        // (e) barrier: drains vm (next tile landed) + keeps buffers coherent
        __syncthreads();
    }

    // ---------------- phase 4: cross-wave PV reduce (Cred aliases UN) ----------------
    float (*Cred)[16][68] = (float (*)[16][68])UN;
    #pragma unroll
    for (int nd = 0; nd < 4; nd++)
        #pragma unroll
        for (int r = 0; r < 4; r++)
            Cred[wid][g * 4 + r][nd * 16 + c] = cacc[nd][r];
    __syncthreads();

    {
        const int q  = tid >> 4;          // 0..15
        const int dq = (tid & 15) * 4;    // 0..60
        f32x4 s = *(const f32x4*)(&Cred[0][q][dq]);
        #pragma unroll
        for (int w = 1; w < 4; w++) {
            f32x4 t2 = *(const f32x4*)(&Cred[w][q][dq]);
            #pragma unroll
            for (int j = 0; j < 4; j++) s[j] += t2[j];
        }
        short4v cb;
        #pragma unroll
        for (int j = 0; j < 4; j++) cb[j] = (short)f2bf(s[j]);
        *(short4v*)(ctx_bf + (size_t)(b * 2048 + qrow + q) * 512 + h * 64 + dq) = cb;
    }
}

// =====================================================================
// Kernel 3: out = ctx @ Wo^T + bo (unchanged).
// =====================================================================
__global__ __launch_bounds__(256) void out_gemm(
    const unsigned short* __restrict__ A,
    const float* __restrict__ Wo, const float* __restrict__ bo,
    float* __restrict__ out)
{
    __shared__ unsigned short As[128 * 40];
    __shared__ unsigned short Bs[128 * 40];

    const int tid  = threadIdx.x;
    const int lane = tid & 63;
    const int wid  = tid >> 6;
    const int g = lane >> 4, c = lane & 15;
    const int wr = wid >> 1, wc = wid & 1;
    const int bm    = blockIdx.x;
    const int ntile = blockIdx.y;

    const unsigned short* Abase = A + (size_t)bm * 128 * 512;
    const float* Bbase = Wo + (size_t)ntile * 128 * 512;

    f32x4 acc[4][4];
    #pragma unroll
    for (int m = 0; m < 4; m++)
        #pragma unroll
        for (int n = 0; n < 4; n++) acc[m][n] = (f32x4){0.f, 0.f, 0.f, 0.f};

    for (int kk = 0; kk < 512; kk += 32) {
        #pragma unroll
        for (int i = 0; i < 2; i++) {
            int f8 = i * 256 + tid;
            int rr = f8 >> 2;
            int cc = (f8 & 3) * 8;
            short8 va = *(const short8*)(Abase + (size_t)rr * 512 + kk + cc);
            *(short8*)(&As[rr * 40 + cc]) = va;
        }
        #pragma unroll
        for (int i = 0; i < 4; i++) {
            int f  = i * 256 + tid;
            int rr = f >> 3;
            int cc = (f & 7) * 4;
            f32x4 vb = *(const f32x4*)(Bbase + (size_t)rr * 512 + kk + cc);
            short4v sb;
            #pragma unroll
            for (int q = 0; q < 4; q++) sb[q] = (short)f2bf(vb[q]);
            *(short4v*)(&Bs[rr * 40 + cc]) = sb;
        }
        __syncthreads();

        short8 af[4], bfr[4];
        #pragma unroll
        for (int m = 0; m < 4; m++) af[m]  = *(const short8*)(&As[(wr * 64 + m * 16 + c) * 40 + g * 8]);
        #pragma unroll
        for (int n = 0; n < 4; n++) bfr[n] = *(const short8*)(&Bs[(wc * 64 + n * 16 + c) * 40 + g * 8]);
        #pragma unroll
        for (int m = 0; m < 4; m++)
            #pragma unroll
            for (int n = 0; n < 4; n++)
                acc[m][n] = MFMA16(af[m], bfr[n], acc[m][n]);
        __syncthreads();
    }

    #pragma unroll
    for (int n = 0; n < 4; n++) {
        int col = ntile * 128 + wc * 64 + n * 16 + c;
        float bb = bo[col];
        #pragma unroll
        for (int m = 0; m < 4; m++) {
            #pragma unroll
            for (int r = 0; r < 4; r++) {
                int row = bm * 128 + wr * 64 + m * 16 + g * 4 + r;
                out[(size_t)row * 512 + col] = acc[m][n][r] + bb;
            }
        }
    }
}

// =====================================================================
extern "C" void kernel_launch(void* const* d_in, const int* in_sizes, int n_in,
                              void* d_out, int out_size, void* d_ws, size_t ws_size,
                              hipStream_t stream)
{
    const float* x    = (const float*)d_in[0];
    const float* dist = (const float*)d_in[1];
    const int*   mask = (const int*)d_in[2];
    const float* Wq   = (const float*)d_in[3];
    const float* bq   = (const float*)d_in[4];
    const float* Wk   = (const float*)d_in[5];
    const float* bk   = (const float*)d_in[6];
    const float* Wv   = (const float*)d_in[7];
    const float* bv   = (const float*)d_in[8];
    const float* Wo   = (const float*)d_in[9];
    const float* bo   = (const float*)d_in[10];

    float* out      = (float*)d_out;            // (2,2048,512)
    float* attn_out = out + 2097152;            // (2,8,2048,2048)

    char* ws = (char*)d_ws;
    unsigned short* Qb  = (unsigned short*)(ws);                 // 4 MB
    unsigned short* Kb  = (unsigned short*)(ws + (4u << 20));    // 4 MB
    unsigned short* Vb  = (unsigned short*)(ws + (8u << 20));    // 4 MB (linear V)
    unsigned short* Vt  = (unsigned short*)(ws + (12u << 20));   // 4 MB [16][64][2048]
    unsigned short* ctx = (unsigned short*)(ws + (8u << 20));    // reuses Vb

    qkv_gemm   <<<dim3(32, 12), 256, 0, stream>>>(x, Wq, bq, Wk, bk, Wv, bv, Qb, Kb, Vb);
    v_transpose<<<dim3(32, 16), 256, 0, stream>>>(Vb, Vt);
    attn_kernel<<<dim3(128, 16), 256, 0, stream>>>(Qb, Kb, Vt, dist, mask, attn_out, ctx);
    out_gemm   <<<dim3(32, 4),  256, 0, stream>>>(ctx, Wo, bo, out);
}